// Round 1
// baseline (44.578 us; speedup 1.0000x reference)
//
#include <hip/hip_runtime.h>
#include <math.h>

#define DIM 1024
#define D4  (DIM / 4)
#define SNUM 5
#define EPSL 1e-6f
#define MARGINL 1.0f

__device__ __forceinline__ float sq4(const float4& x, const float4& y) {
    float dx = x.x - y.x + EPSL;
    float dy = x.y - y.y + EPSL;
    float dz = x.z - y.z + EPSL;
    float dw = x.w - y.w + EPSL;
    return dx * dx + dy * dy + dz * dz + dw * dw;
}

// One block (256 threads = 4 waves) per anchor k. Each thread owns one float4
// slice of the D=1024 row. 11 partial sums (1 pos + 5 neg1 + 5 neg2) reduced
// via 64-lane shuffles then a [4][11] LDS hop.
__global__ __launch_bounds__(256) void hinge_kernel(const float* __restrict__ vfeat,
                                                    const float* __restrict__ afeat,
                                                    float* __restrict__ hinge,
                                                    int B) {
    const int k = blockIdx.x;
    const int t = threadIdx.x;
    const float4* __restrict__ v4 = reinterpret_cast<const float4*>(vfeat);
    const float4* __restrict__ a4 = reinterpret_cast<const float4*>(afeat);

    const float4 vk = v4[(size_t)k * D4 + t];
    const float4 ak = a4[(size_t)k * D4 + t];

    float acc[11];
    acc[0] = sq4(vk, ak);  // positive

    #pragma unroll
    for (int m = 0; m < SNUM; ++m) {
        int j = (m + k + 1) % B;
        if (m == k) j = (k + 1) % B;
        const float4 aj = a4[(size_t)j * D4 + t];
        const float4 vj = v4[(size_t)j * D4 + t];
        acc[1 + m]        = sq4(vk, aj);  // d_n1 partial
        acc[1 + SNUM + m] = sq4(ak, vj);  // d_n2 partial
    }

    // 64-lane wave reduction
    #pragma unroll
    for (int off = 32; off > 0; off >>= 1) {
        #pragma unroll
        for (int i = 0; i < 11; ++i)
            acc[i] += __shfl_down(acc[i], off, 64);
    }

    __shared__ float red[4][11];
    const int wave = t >> 6;
    const int lane = t & 63;
    if (lane == 0) {
        #pragma unroll
        for (int i = 0; i < 11; ++i) red[wave][i] = acc[i];
    }
    __syncthreads();

    if (t == 0) {
        float tot[11];
        #pragma unroll
        for (int i = 0; i < 11; ++i)
            tot[i] = red[0][i] + red[1][i] + red[2][i] + red[3][i];

        const float d_p = sqrtf(tot[0]);
        float dn1 = sqrtf(tot[1]);
        float dn2 = sqrtf(tot[1 + SNUM]);
        #pragma unroll
        for (int m = 1; m < SNUM; ++m) {
            dn1 = fminf(dn1, sqrtf(tot[1 + m]));
            dn2 = fminf(dn2, sqrtf(tot[1 + SNUM + m]));
        }
        hinge[k] = fmaxf(MARGINL + 2.0f * d_p - dn1 - dn2, 0.0f);
    }
}

// Deterministic single-block mean of hinge[0..B)
__global__ __launch_bounds__(256) void mean_kernel(const float* __restrict__ hinge,
                                                   float* __restrict__ out, int B) {
    const int t = threadIdx.x;
    float s = 0.0f;
    for (int i = t; i < B; i += 256) s += hinge[i];

    #pragma unroll
    for (int off = 32; off > 0; off >>= 1)
        s += __shfl_down(s, off, 64);

    __shared__ float red[4];
    if ((t & 63) == 0) red[t >> 6] = s;
    __syncthreads();
    if (t == 0) {
        float tot = red[0] + red[1] + red[2] + red[3];
        out[0] = tot / (float)B;
    }
}

extern "C" void kernel_launch(void* const* d_in, const int* in_sizes, int n_in,
                              void* d_out, int out_size, void* d_ws, size_t ws_size,
                              hipStream_t stream) {
    const float* vfeat = (const float*)d_in[0];
    const float* afeat = (const float*)d_in[1];
    const int B = in_sizes[0] / DIM;

    float* hinge = (float*)d_ws;   // B floats of scratch
    float* out   = (float*)d_out;

    hinge_kernel<<<B, 256, 0, stream>>>(vfeat, afeat, hinge, B);
    mean_kernel<<<1, 256, 0, stream>>>(hinge, out, B);
}

// Round 2
// 23.875 us; speedup vs baseline: 1.8672x; 1.8672x over previous
//
#include <hip/hip_runtime.h>
#include <math.h>

#define DIM 1024
#define D4  (DIM / 4)
#define SNUM 5
#define EPSL 1e-6f
#define MARGINL 1.0f

__device__ __forceinline__ float sq4(const float4& x, const float4& y) {
    float dx = x.x - y.x + EPSL;
    float dy = x.y - y.y + EPSL;
    float dz = x.z - y.z + EPSL;
    float dw = x.w - y.w + EPSL;
    return dx * dx + dy * dy + dz * dz + dw * dw;
}

// One block (256 threads = 4 waves) per anchor k. blockIdx -> anchor mapping is
// XCD-chunk swizzled: block i runs on XCD i%8 (round-robin dispatch), so we give
// each XCD a contiguous range of anchors. Anchor k's neighbor rows k+1..k+5 are
// then re-read from the same XCD's L2 instead of a remote one / L3 / HBM.
__global__ __launch_bounds__(256) void hinge_kernel(const float* __restrict__ vfeat,
                                                    const float* __restrict__ afeat,
                                                    float* __restrict__ hinge,
                                                    int B) {
    int k = blockIdx.x;
    if ((B & 7) == 0) {
        const int chunk = B >> 3;                 // anchors per XCD
        k = (k & 7) * chunk + (k >> 3);           // bijective chunked swizzle
    }
    const int t = threadIdx.x;
    const float4* __restrict__ v4 = reinterpret_cast<const float4*>(vfeat);
    const float4* __restrict__ a4 = reinterpret_cast<const float4*>(afeat);

    const float4 vk = v4[(size_t)k * D4 + t];
    const float4 ak = a4[(size_t)k * D4 + t];

    float acc[11];
    acc[0] = sq4(vk, ak);  // positive

    #pragma unroll
    for (int m = 0; m < SNUM; ++m) {
        int j = (m + k + 1) % B;
        if (m == k) j = (k + 1) % B;
        const float4 aj = a4[(size_t)j * D4 + t];
        const float4 vj = v4[(size_t)j * D4 + t];
        acc[1 + m]        = sq4(vk, aj);  // d_n1 partial
        acc[1 + SNUM + m] = sq4(ak, vj);  // d_n2 partial
    }

    // 64-lane wave reduction
    #pragma unroll
    for (int off = 32; off > 0; off >>= 1) {
        #pragma unroll
        for (int i = 0; i < 11; ++i)
            acc[i] += __shfl_down(acc[i], off, 64);
    }

    __shared__ float red[4][11];
    const int wave = t >> 6;
    const int lane = t & 63;
    if (lane == 0) {
        #pragma unroll
        for (int i = 0; i < 11; ++i) red[wave][i] = acc[i];
    }
    __syncthreads();

    if (t == 0) {
        float tot[11];
        #pragma unroll
        for (int i = 0; i < 11; ++i)
            tot[i] = red[0][i] + red[1][i] + red[2][i] + red[3][i];

        const float d_p = sqrtf(tot[0]);
        float dn1 = sqrtf(tot[1]);
        float dn2 = sqrtf(tot[1 + SNUM]);
        #pragma unroll
        for (int m = 1; m < SNUM; ++m) {
            dn1 = fminf(dn1, sqrtf(tot[1 + m]));
            dn2 = fminf(dn2, sqrtf(tot[1 + SNUM + m]));
        }
        hinge[k] = fmaxf(MARGINL + 2.0f * d_p - dn1 - dn2, 0.0f);
    }
}

// Deterministic single-block mean of hinge[0..B)
__global__ __launch_bounds__(1024) void mean_kernel(const float* __restrict__ hinge,
                                                    float* __restrict__ out, int B) {
    const int t = threadIdx.x;
    float s = 0.0f;
    for (int i = t; i < B; i += 1024) s += hinge[i];

    #pragma unroll
    for (int off = 32; off > 0; off >>= 1)
        s += __shfl_down(s, off, 64);

    __shared__ float red[16];
    if ((t & 63) == 0) red[t >> 6] = s;
    __syncthreads();
    if (t == 0) {
        float tot = 0.0f;
        #pragma unroll
        for (int w = 0; w < 16; ++w) tot += red[w];
        out[0] = tot / (float)B;
    }
}

extern "C" void kernel_launch(void* const* d_in, const int* in_sizes, int n_in,
                              void* d_out, int out_size, void* d_ws, size_t ws_size,
                              hipStream_t stream) {
    const float* vfeat = (const float*)d_in[0];
    const float* afeat = (const float*)d_in[1];
    const int B = in_sizes[0] / DIM;

    float* hinge = (float*)d_ws;   // B floats of scratch
    float* out   = (float*)d_out;

    hinge_kernel<<<B, 256, 0, stream>>>(vfeat, afeat, hinge, B);
    mean_kernel<<<1, 1024, 0, stream>>>(hinge, out, B);
}